// Round 14
// baseline (256.952 us; speedup 1.0000x reference)
//
#include <hip/hip_runtime.h>
#include <math.h>

#define BB 8
#define NN 1024
#define IND 128
#define DD 32
#define HH 8
#define KT 64   // key tile
#define QT 64   // query rows per block

// ---------------------------------------------------------------------------
// ws layout:
//   Q [B,H,N,D] f32, K, V  (8.39 MB each)
//   A8 [B,N,N] u8          (8.39 MB)
//   sums: double[128] (4 used, 256B apart), cnt: u64[64] (cnt[0], cnt[32])
//   part: float[2048][64][40]  (21 MB; split path)
// R12 post-mortem: attn busy phase is LDS/issue-bound (VALUBusy 29%), tail
// theory mostly disproven (S=2 bought 7%). attn left untouched this round.
// R13: proj inner loop was scalar ds_read_b32 (1024/thread, LDS-bound);
// now float4 k-unroll (stride 132 = 16B-aligned rows, conflict-free) ->
// VALU-bound. pack widened to 2048 blocks.
// ---------------------------------------------------------------------------

__global__ __launch_bounds__(256) void proj_kernel(
    const float* __restrict__ h,
    const float* __restrict__ Wq, const float* __restrict__ bq,
    const float* __restrict__ Wk, const float* __restrict__ bk,
    const float* __restrict__ Wv, const float* __restrict__ bv,
    const int* __restrict__ lengths,
    float* __restrict__ Q, float* __restrict__ K, float* __restrict__ V)
{
    const int cb = blockIdx.x;
    const int rb = blockIdx.y;
    if (((rb & 15) * 64) >= lengths[rb >> 4]) return;

    const int t  = threadIdx.x;
    // stride 132 floats = 528B/row: 16B-aligned (ds_read_b128) and
    // consecutive rows land 4 banks apart (2-way max conflict = free).
    __shared__ float Xs[64][132];
    __shared__ float Ws[64][132];

    const int which = cb >> 2;            // 0=q 1=k 2=v
    const int c0    = (cb & 3) * 64;
    const float* Wsrc = (which == 0) ? Wq : (which == 1) ? Wk : Wv;
    const float* bsrc = (which == 0) ? bq : (which == 1) ? bk : bv;
    float* Out        = (which == 0) ? Q  : (which == 1) ? K  : V;

    #pragma unroll
    for (int i = 0; i < 8; ++i) {
        int e = (i * 256 + t) * 4;
        int r = e >> 7;
        int c = e & 127;
        *(float4*)&Xs[r][c] = *(const float4*)(&h[(size_t)(rb * 64 + r) * IND + c]);
        *(float4*)&Ws[r][c] = *(const float4*)(&Wsrc[(size_t)(c0 + r) * IND + c]);
    }
    __syncthreads();

    // thread (tr=t>>4, tc=t&15) computes rows {tr+16i}, cols {tc+16j}
    const int tr = t >> 4;
    const int tc = t & 15;
    float acc[4][4] = {};
    for (int k = 0; k < IND; k += 4) {
        float4 xa[4], wb[4];
        #pragma unroll
        for (int i = 0; i < 4; ++i) xa[i] = *(const float4*)&Xs[tr + i * 16][k];
        #pragma unroll
        for (int j = 0; j < 4; ++j) wb[j] = *(const float4*)&Ws[tc + j * 16][k];
        #pragma unroll
        for (int i = 0; i < 4; ++i) {
            #pragma unroll
            for (int j = 0; j < 4; ++j) {
                acc[i][j] = fmaf(xa[i].x, wb[j].x, acc[i][j]);
                acc[i][j] = fmaf(xa[i].y, wb[j].y, acc[i][j]);
                acc[i][j] = fmaf(xa[i].z, wb[j].z, acc[i][j]);
                acc[i][j] = fmaf(xa[i].w, wb[j].w, acc[i][j]);
            }
        }
    }

    #pragma unroll
    for (int i = 0; i < 4; ++i) {
        int r = rb * 64 + tr + i * 16;
        int bb = r >> 10, n = r & 1023;
        #pragma unroll
        for (int j = 0; j < 4; ++j) {
            int o = tc + j * 16 + c0;
            int hh = o >> 5, dd = o & 31;
            Out[(((size_t)bb * HH + hh) * NN + n) * DD + dd] = acc[i][j] + bsrc[o];
        }
    }
}

__global__ __launch_bounds__(256) void pack_kernel(
    const int* __restrict__ A, unsigned char* __restrict__ A8,
    unsigned long long* __restrict__ cnt)
{
    const int NT = (BB * NN * NN) / 4;
    unsigned c1 = 0, c2 = 0;
    for (int idx = blockIdx.x * 256 + threadIdx.x; idx < NT; idx += gridDim.x * 256) {
        int4 a = *(const int4*)&A[(size_t)idx * 4];
        unsigned packed = (unsigned)(a.x & 0xff) | ((unsigned)(a.y & 0xff) << 8) |
                          ((unsigned)(a.z & 0xff) << 16) | ((unsigned)(a.w & 0xff) << 24);
        *(unsigned*)&A8[(size_t)idx * 4] = packed;
        c1 += (a.x == 1) + (a.y == 1) + (a.z == 1) + (a.w == 1);
        c2 += (a.x > 1) + (a.y > 1) + (a.z > 1) + (a.w > 1);
    }
    #pragma unroll
    for (int off = 32; off; off >>= 1) {
        c1 += __shfl_down(c1, off);
        c2 += __shfl_down(c2, off);
    }
    __shared__ unsigned r1[4], r2[4];
    const int wave = threadIdx.x >> 6;
    if ((threadIdx.x & 63) == 0) { r1[wave] = c1; r2[wave] = c2; }
    __syncthreads();
    if (threadIdx.x == 0) {
        unsigned long long t1 = (unsigned long long)r1[0] + r1[1] + r1[2] + r1[3];
        unsigned long long t2 = (unsigned long long)r2[0] + r2[1] + r2[2] + r2[3];
        atomicAdd(&cnt[0], t1);
        atomicAdd(&cnt[32], t2);
    }
}

// ---- grid-level 2-way K-split + merge (unchanged from R12) -----------------
__global__ __launch_bounds__(256) void attn_split_kernel(
    const float* __restrict__ Q, const float* __restrict__ Kg, const float* __restrict__ Vg,
    const unsigned char* __restrict__ A8,
    const int* __restrict__ lengths, const float* __restrict__ alpha,
    float* __restrict__ part)
{
    const int bidAll = blockIdx.x;
    const int split = bidAll >> 10;
    const int bid = bidAll & 1023;
    const int qt = bid & 15;
    const int hh = (bid >> 4) & 7;
    const int b  = bid >> 7;
    const int t  = threadIdx.x;
    const int qg = t >> 3;
    const int lane8 = t & 7;

    const int len = lengths[b];
    const size_t base = ((size_t)b * HH + hh) * NN * DD;

    if (qt * QT >= len) return;     // merge zero-fills padded q-blocks

    __shared__ float Qs[QT][36];
    __shared__ float Ks[KT][36];
    __shared__ float Vs[KT][36];
    __shared__ unsigned char As[QT][80];

    const float al  = alpha[0];
    const float l2a = __log2f(al);
    const float scale = 0.17677669529663687f;

    const int sr = t >> 3;
    const int sc = ((t & 7) - sr) & 7;

    #pragma unroll
    for (int i = 0; i < 2; ++i) {
        int r = i * 32 + sr;
        float4 v = *(const float4*)&Q[base + (size_t)(qt * QT + r) * DD + sc * 4];
        v.x *= scale; v.y *= scale; v.z *= scale; v.w *= scale;
        *(float4*)&Qs[r][sc * 4] = v;
    }

    float m0 = -1e30f, m1 = -1e30f, l0 = 0.f, l1 = 0.f;
    float acc0[32], acc1[32];
    #pragma unroll
    for (int d = 0; d < 32; ++d) { acc0[d] = 0.f; acc1[d] = 0.f; }
    float pr0_1 = 0.f, pr0_2 = 0.f, po0_1 = 0.f, po0_2 = 0.f;
    float pr1_1 = 0.f, pr1_2 = 0.f, po1_1 = 0.f, po1_2 = 0.f;

    const int ntiles = (len + KT - 1) / KT;
    const int htiles = (ntiles + 1) >> 1;
    const int t0 = split * htiles;
    const int t1 = (ntiles < t0 + htiles) ? ntiles : (t0 + htiles);

    for (int tt = t0; tt < t1; ++tt) {
        const int j0 = tt * KT;
        __syncthreads();
        #pragma unroll
        for (int i = 0; i < 2; ++i) {
            int r = i * 32 + sr;
            *(float4*)&Ks[r][sc * 4] = *(const float4*)&Kg[base + (size_t)(j0 + r) * DD + sc * 4];
            *(float4*)&Vs[r][sc * 4] = *(const float4*)&Vg[base + (size_t)(j0 + r) * DD + sc * 4];
        }
        {
            int r = t >> 2, c = (t & 3) * 16;
            *(int4*)&As[r][c] = *(const int4*)&A8[((size_t)b * NN + qt * QT + r) * NN + j0 + c];
        }
        __syncthreads();

        float s0[8], s1[8];
        #pragma unroll
        for (int e = 0; e < 8; ++e) { s0[e] = 0.f; s1[e] = 0.f; }
        #pragma unroll
        for (int i = 0; i < 8; ++i) {
            float4 qa = *(const float4*)&Qs[qg][i * 4];
            float4 qb = *(const float4*)&Qs[qg + 32][i * 4];
            #pragma unroll
            for (int e = 0; e < 8; ++e) {
                float4 kv = *(const float4*)&Ks[e * 8 + lane8][i * 4];
                s0[e] = fmaf(qa.x, kv.x, s0[e]); s0[e] = fmaf(qa.y, kv.y, s0[e]);
                s0[e] = fmaf(qa.z, kv.z, s0[e]); s0[e] = fmaf(qa.w, kv.w, s0[e]);
                s1[e] = fmaf(qb.x, kv.x, s1[e]); s1[e] = fmaf(qb.y, kv.y, s1[e]);
                s1[e] = fmaf(qb.z, kv.z, s1[e]); s1[e] = fmaf(qb.w, kv.w, s1[e]);
            }
        }

        float tm0 = -INFINITY, tm1 = -INFINITY;
        #pragma unroll
        for (int e = 0; e < 8; ++e) {
            bool valid = (j0 + e * 8 + lane8) < len;
            s0[e] = valid ? s0[e] : -INFINITY;
            s1[e] = valid ? s1[e] : -INFINITY;
            tm0 = fmaxf(tm0, s0[e]); tm1 = fmaxf(tm1, s1[e]);
        }
        #pragma unroll
        for (int off = 1; off < 8; off <<= 1) {
            tm0 = fmaxf(tm0, __shfl_xor(tm0, off, 8));
            tm1 = fmaxf(tm1, __shfl_xor(tm1, off, 8));
        }
        if (tm0 > m0) {
            float scl = __expf(m0 - tm0);
            l0 *= scl; pr0_1 *= scl; pr0_2 *= scl; po0_1 *= scl; po0_2 *= scl;
            #pragma unroll
            for (int d = 0; d < 32; ++d) acc0[d] *= scl;
            m0 = tm0;
        }
        if (tm1 > m1) {
            float scl = __expf(m1 - tm1);
            l1 *= scl; pr1_1 *= scl; pr1_2 *= scl; po1_1 *= scl; po1_2 *= scl;
            #pragma unroll
            for (int d = 0; d < 32; ++d) acc1[d] *= scl;
            m1 = tm1;
        }

        #pragma unroll
        for (int e = 0; e < 8; ++e) {
            int j = e * 8 + lane8;
            float pe0 = __expf(s0[e] - m0);
            float pe1 = __expf(s1[e] - m1);
            l0 += pe0; l1 += pe1;
            int a0 = As[qg][j], a1 = As[qg + 32][j];
            float w0 = exp2f((float)a0 * l2a);
            float w1 = exp2f((float)a1 * l2a);
            float pw0 = pe0 * w0, pw1 = pe1 * w1;
            pr0_1 += (a0 == 1) ? pe0 : 0.f;  pr0_2 += (a0 > 1) ? pe0 : 0.f;
            po0_1 += (a0 == 1) ? pw0 : 0.f;  po0_2 += (a0 > 1) ? pw0 : 0.f;
            pr1_1 += (a1 == 1) ? pe1 : 0.f;  pr1_2 += (a1 > 1) ? pe1 : 0.f;
            po1_1 += (a1 == 1) ? pw1 : 0.f;  po1_2 += (a1 > 1) ? pw1 : 0.f;
            s0[e] = pw0; s1[e] = pw1;
        }

        #pragma unroll
        for (int e = 0; e < 8; ++e) {
            float pw0 = s0[e], pw1 = s1[e];
            #pragma unroll
            for (int i = 0; i < 8; ++i) {
                float4 vv = *(const float4*)&Vs[e * 8 + lane8][i * 4];
                acc0[i * 4 + 0] = fmaf(pw0, vv.x, acc0[i * 4 + 0]);
                acc0[i * 4 + 1] = fmaf(pw0, vv.y, acc0[i * 4 + 1]);
                acc0[i * 4 + 2] = fmaf(pw0, vv.z, acc0[i * 4 + 2]);
                acc0[i * 4 + 3] = fmaf(pw0, vv.w, acc0[i * 4 + 3]);
                acc1[i * 4 + 0] = fmaf(pw1, vv.x, acc1[i * 4 + 0]);
                acc1[i * 4 + 1] = fmaf(pw1, vv.y, acc1[i * 4 + 1]);
                acc1[i * 4 + 2] = fmaf(pw1, vv.z, acc1[i * 4 + 2]);
                acc1[i * 4 + 3] = fmaf(pw1, vv.w, acc1[i * 4 + 3]);
            }
        }
    }

    #pragma unroll
    for (int off = 1; off < 8; off <<= 1) {
        l0 += __shfl_xor(l0, off, 8);       l1 += __shfl_xor(l1, off, 8);
        pr0_1 += __shfl_xor(pr0_1, off, 8); pr0_2 += __shfl_xor(pr0_2, off, 8);
        po0_1 += __shfl_xor(po0_1, off, 8); po0_2 += __shfl_xor(po0_2, off, 8);
        pr1_1 += __shfl_xor(pr1_1, off, 8); pr1_2 += __shfl_xor(pr1_2, off, 8);
        po1_1 += __shfl_xor(po1_1, off, 8); po1_2 += __shfl_xor(po1_2, off, 8);
        #pragma unroll
        for (int d = 0; d < 32; ++d) {
            acc0[d] += __shfl_xor(acc0[d], off, 8);
            acc1[d] += __shfl_xor(acc1[d], off, 8);
        }
    }

    const int dsl = lane8 * 4;
    float* st0 = part + (((size_t)split * 1024 + bid) * 64 + qg) * 40;
    float* st1 = st0 + 32 * 40;
    if (lane8 == 0) {
        st0[0] = m0; st0[1] = l0; st0[2] = pr0_1; st0[3] = pr0_2; st0[4] = po0_1; st0[5] = po0_2;
        st1[0] = m1; st1[1] = l1; st1[2] = pr1_1; st1[3] = pr1_2; st1[4] = po1_1; st1[5] = po1_2;
    }
    *(float4*)&st0[8 + dsl] = make_float4(acc0[dsl], acc0[dsl + 1], acc0[dsl + 2], acc0[dsl + 3]);
    *(float4*)&st1[8 + dsl] = make_float4(acc1[dsl], acc1[dsl + 1], acc1[dsl + 2], acc1[dsl + 3]);
}

__global__ __launch_bounds__(256) void merge_kernel(
    const float* __restrict__ part, const int* __restrict__ lengths,
    float* __restrict__ out, double* __restrict__ sums)
{
    const int bid = blockIdx.x;
    const int qt = bid & 15;
    const int hh = (bid >> 4) & 7;
    const int b  = bid >> 7;
    const int t  = threadIdx.x;
    const int qg = t >> 3;
    const int lane8 = t & 7;
    const int dsl = lane8 * 4;
    const int len = lengths[b];
    const size_t base = ((size_t)b * HH + hh) * NN * DD;

    if (qt * QT >= len) {
        float4 z = make_float4(0.f, 0.f, 0.f, 0.f);
        *(float4*)&out[base + (size_t)(qt * QT + qg) * DD + dsl] = z;
        *(float4*)&out[base + (size_t)(qt * QT + qg + 32) * DD + dsl] = z;
        return;
    }

    float v1 = 0.f, v2 = 0.f, v3 = 0.f, v4 = 0.f;
    #pragma unroll
    for (int rr = 0; rr < 2; ++rr) {
        const int row = qg + rr * 32;
        const int gq = qt * QT + row;
        const float* sA = part + (((size_t)0 * 1024 + bid) * 64 + row) * 40;
        const float* sB = part + (((size_t)1 * 1024 + bid) * 64 + row) * 40;
        float mA = sA[0], lA = sA[1], mB = sB[0], lB = sB[1];
        float ms = fmaxf(mA, mB);
        float fA = __expf(mA - ms), fB = __expf(mB - ms);
        float L = lA * fA + lB * fB;
        float inv = (gq < len) ? 1.f / L : 0.f;
        float4 aA = *(const float4*)&sA[8 + dsl];
        float4 aB = *(const float4*)&sB[8 + dsl];
        float4 o;
        o.x = (aA.x * fA + aB.x * fB) * inv;
        o.y = (aA.y * fA + aB.y * fB) * inv;
        o.z = (aA.z * fA + aB.z * fB) * inv;
        o.w = (aA.w * fA + aB.w * fB) * inv;
        *(float4*)&out[base + (size_t)gq * DD + dsl] = o;
        if (lane8 == 0) {
            v1 += (sA[2] * fA + sB[2] * fB) * inv;
            v2 += (sA[3] * fA + sB[3] * fB) * inv;
            v3 += (sA[4] * fA + sB[4] * fB) * inv;
            v4 += (sA[5] * fA + sB[5] * fB) * inv;
        }
    }

    __shared__ float red4[4][4];
    #pragma unroll
    for (int off = 1; off < 64; off <<= 1) {
        v1 += __shfl_xor(v1, off);
        v2 += __shfl_xor(v2, off);
        v3 += __shfl_xor(v3, off);
        v4 += __shfl_xor(v4, off);
    }
    const int wv = t >> 6;
    if ((t & 63) == 0) { red4[0][wv] = v1; red4[1][wv] = v2; red4[2][wv] = v3; red4[3][wv] = v4; }
    __syncthreads();
    if (t < 4) {
        float s = red4[t][0] + red4[t][1] + red4[t][2] + red4[t][3];
        atomicAdd(&sums[t * 32], (double)s);
    }
}

__global__ void fin_kernel(const double* __restrict__ sums,
                           const unsigned long long* __restrict__ cnt,
                           float* __restrict__ outtail)
{
    if (threadIdx.x == 0) {
        double c1 = (double)(cnt[0] * (unsigned long long)HH);
        double c2 = (double)(cnt[32] * (unsigned long long)HH);
        outtail[0] = (float)(sums[0]  / c1);
        outtail[1] = (float)(sums[32] / c2);
        outtail[2] = (float)(sums[64] / c1);
        outtail[3] = (float)(sums[96] / c2);
    }
}

extern "C" void kernel_launch(void* const* d_in, const int* in_sizes, int n_in,
                              void* d_out, int out_size, void* d_ws, size_t ws_size,
                              hipStream_t stream)
{
    const float* h   = (const float*)d_in[0];
    const int* A     = (const int*)d_in[1];
    const int* lens  = (const int*)d_in[2];
    const float* alp = (const float*)d_in[3];
    const float* Wq  = (const float*)d_in[4];
    const float* bq  = (const float*)d_in[5];
    const float* Wk  = (const float*)d_in[6];
    const float* bk  = (const float*)d_in[7];
    const float* Wv  = (const float*)d_in[8];
    const float* bv  = (const float*)d_in[9];

    float* outF = (float*)d_out;

    const size_t qkv = (size_t)BB * HH * NN * DD;
    float* Qw = (float*)d_ws;
    float* Kw = Qw + qkv;
    float* Vw = Kw + qkv;
    unsigned char* A8 = (unsigned char*)(Vw + qkv);
    double* sums = (double*)(A8 + (size_t)BB * NN * NN);
    unsigned long long* cnt = (unsigned long long*)(sums + 128);
    float* part = (float*)(cnt + 64);

    (void)hipMemsetAsync(sums, 0, 128 * sizeof(double) + 64 * sizeof(unsigned long long), stream);

    proj_kernel<<<dim3(12, 128), 256, 0, stream>>>(h, Wq, bq, Wk, bk, Wv, bv, lens, Qw, Kw, Vw);
    pack_kernel<<<2048, 256, 0, stream>>>(A, A8, cnt);
    attn_split_kernel<<<2048, 256, 0, stream>>>(Qw, Kw, Vw, A8, lens, alp, part);
    merge_kernel<<<1024, 256, 0, stream>>>(part, lens, outF, sums);
    fin_kernel<<<1, 64, 0, stream>>>(sums, cnt, outF + qkv);
}

// Round 15
// 254.726 us; speedup vs baseline: 1.0087x; 1.0087x over previous
//
#include <hip/hip_runtime.h>
#include <math.h>

#define BB 8
#define NN 1024
#define IND 128
#define DD 32
#define HH 8
#define KT 64   // key tile
#define QT 64   // query rows per block
#define PROJ_BLOCKS 1536
#define PACK_BLOCKS 1024

// ---------------------------------------------------------------------------
// ws layout:
//   Q [B,H,N,D] f32, K, V  (8.39 MB each)
//   A8 [B,N,N] u8          (8.39 MB)
//   sums double[128] | cnt u64[64] | done u32[4] | part float[2048][64][40]
// R14 post-mortem: proj rewrite NEUTRAL; kernel-sum by roofline ~150us vs
// 257 measured -> ~110us is either inter-dispatch gaps or a mystery-slow
// proj. R15: fuse proj+pack (independent) and fin->merge (completion
// counter). 5 kernels -> 3. If gaps: total ~215. If proj slow: projpack
// surfaces in top-5 -> next target identified.
// ---------------------------------------------------------------------------

__global__ __launch_bounds__(256) void projpack_kernel(
    const float* __restrict__ h,
    const float* __restrict__ Wq, const float* __restrict__ bq,
    const float* __restrict__ Wk, const float* __restrict__ bk,
    const float* __restrict__ Wv, const float* __restrict__ bv,
    const int* __restrict__ lengths,
    const int* __restrict__ A,
    float* __restrict__ Q, float* __restrict__ K, float* __restrict__ V,
    unsigned char* __restrict__ A8, unsigned long long* __restrict__ cnt)
{
    const int t = threadIdx.x;

    if (blockIdx.x >= PROJ_BLOCKS) {
        // ---- pack role: A int32 -> u8, count m1/m2 --------------------------
        const int pb = blockIdx.x - PROJ_BLOCKS;
        const int NT = (BB * NN * NN) / 4;
        unsigned c1 = 0, c2 = 0;
        for (int idx = pb * 256 + t; idx < NT; idx += PACK_BLOCKS * 256) {
            int4 a = *(const int4*)&A[(size_t)idx * 4];
            unsigned packed = (unsigned)(a.x & 0xff) | ((unsigned)(a.y & 0xff) << 8) |
                              ((unsigned)(a.z & 0xff) << 16) | ((unsigned)(a.w & 0xff) << 24);
            *(unsigned*)&A8[(size_t)idx * 4] = packed;
            c1 += (a.x == 1) + (a.y == 1) + (a.z == 1) + (a.w == 1);
            c2 += (a.x > 1) + (a.y > 1) + (a.z > 1) + (a.w > 1);
        }
        #pragma unroll
        for (int off = 32; off; off >>= 1) {
            c1 += __shfl_down(c1, off);
            c2 += __shfl_down(c2, off);
        }
        __shared__ unsigned r1[4], r2[4];
        const int wave = t >> 6;
        if ((t & 63) == 0) { r1[wave] = c1; r2[wave] = c2; }
        __syncthreads();
        if (t == 0) {
            unsigned long long t1 = (unsigned long long)r1[0] + r1[1] + r1[2] + r1[3];
            unsigned long long t2 = (unsigned long long)r2[0] + r2[1] + r2[2] + r2[3];
            atomicAdd(&cnt[0], t1);
            atomicAdd(&cnt[32], t2);
        }
        return;
    }

    // ---- proj role: [64x128] x [128x64] tile of Q/K/V projection -----------
    const int pbid = blockIdx.x;
    const int cb = pbid % 12;
    const int rb = pbid / 12;
    if (((rb & 15) * 64) >= lengths[rb >> 4]) return;

    __shared__ float Xs[64][132];   // stride 132: 16B-aligned rows, conflict-free
    __shared__ float Ws[64][132];

    const int which = cb >> 2;            // 0=q 1=k 2=v
    const int c0    = (cb & 3) * 64;
    const float* Wsrc = (which == 0) ? Wq : (which == 1) ? Wk : Wv;
    const float* bsrc = (which == 0) ? bq : (which == 1) ? bk : bv;
    float* Out        = (which == 0) ? Q  : (which == 1) ? K  : V;

    #pragma unroll
    for (int i = 0; i < 8; ++i) {
        int e = (i * 256 + t) * 4;
        int r = e >> 7;
        int c = e & 127;
        *(float4*)&Xs[r][c] = *(const float4*)(&h[(size_t)(rb * 64 + r) * IND + c]);
        *(float4*)&Ws[r][c] = *(const float4*)(&Wsrc[(size_t)(c0 + r) * IND + c]);
    }
    __syncthreads();

    const int tr = t >> 4;
    const int tc = t & 15;
    float acc[4][4] = {};
    for (int k = 0; k < IND; k += 4) {
        float4 xa[4], wb[4];
        #pragma unroll
        for (int i = 0; i < 4; ++i) xa[i] = *(const float4*)&Xs[tr + i * 16][k];
        #pragma unroll
        for (int j = 0; j < 4; ++j) wb[j] = *(const float4*)&Ws[tc + j * 16][k];
        #pragma unroll
        for (int i = 0; i < 4; ++i) {
            #pragma unroll
            for (int j = 0; j < 4; ++j) {
                acc[i][j] = fmaf(xa[i].x, wb[j].x, acc[i][j]);
                acc[i][j] = fmaf(xa[i].y, wb[j].y, acc[i][j]);
                acc[i][j] = fmaf(xa[i].z, wb[j].z, acc[i][j]);
                acc[i][j] = fmaf(xa[i].w, wb[j].w, acc[i][j]);
            }
        }
    }

    #pragma unroll
    for (int i = 0; i < 4; ++i) {
        int r = rb * 64 + tr + i * 16;
        int bb = r >> 10, n = r & 1023;
        #pragma unroll
        for (int j = 0; j < 4; ++j) {
            int o = tc + j * 16 + c0;
            int hh = o >> 5, dd = o & 31;
            Out[(((size_t)bb * HH + hh) * NN + n) * DD + dd] = acc[i][j] + bsrc[o];
        }
    }
}

// ---- grid-level 2-way K-split (unchanged from R12) -------------------------
__global__ __launch_bounds__(256) void attn_split_kernel(
    const float* __restrict__ Q, const float* __restrict__ Kg, const float* __restrict__ Vg,
    const unsigned char* __restrict__ A8,
    const int* __restrict__ lengths, const float* __restrict__ alpha,
    float* __restrict__ part)
{
    const int bidAll = blockIdx.x;
    const int split = bidAll >> 10;
    const int bid = bidAll & 1023;
    const int qt = bid & 15;
    const int hh = (bid >> 4) & 7;
    const int b  = bid >> 7;
    const int t  = threadIdx.x;
    const int qg = t >> 3;
    const int lane8 = t & 7;

    const int len = lengths[b];
    const size_t base = ((size_t)b * HH + hh) * NN * DD;

    if (qt * QT >= len) return;     // merge zero-fills padded q-blocks

    __shared__ float Qs[QT][36];
    __shared__ float Ks[KT][36];
    __shared__ float Vs[KT][36];
    __shared__ unsigned char As[QT][80];

    const float al  = alpha[0];
    const float l2a = __log2f(al);
    const float scale = 0.17677669529663687f;

    const int sr = t >> 3;
    const int sc = ((t & 7) - sr) & 7;

    #pragma unroll
    for (int i = 0; i < 2; ++i) {
        int r = i * 32 + sr;
        float4 v = *(const float4*)&Q[base + (size_t)(qt * QT + r) * DD + sc * 4];
        v.x *= scale; v.y *= scale; v.z *= scale; v.w *= scale;
        *(float4*)&Qs[r][sc * 4] = v;
    }

    float m0 = -1e30f, m1 = -1e30f, l0 = 0.f, l1 = 0.f;
    float acc0[32], acc1[32];
    #pragma unroll
    for (int d = 0; d < 32; ++d) { acc0[d] = 0.f; acc1[d] = 0.f; }
    float pr0_1 = 0.f, pr0_2 = 0.f, po0_1 = 0.f, po0_2 = 0.f;
    float pr1_1 = 0.f, pr1_2 = 0.f, po1_1 = 0.f, po1_2 = 0.f;

    const int ntiles = (len + KT - 1) / KT;
    const int htiles = (ntiles + 1) >> 1;
    const int t0 = split * htiles;
    const int t1 = (ntiles < t0 + htiles) ? ntiles : (t0 + htiles);

    for (int tt = t0; tt < t1; ++tt) {
        const int j0 = tt * KT;
        __syncthreads();
        #pragma unroll
        for (int i = 0; i < 2; ++i) {
            int r = i * 32 + sr;
            *(float4*)&Ks[r][sc * 4] = *(const float4*)&Kg[base + (size_t)(j0 + r) * DD + sc * 4];
            *(float4*)&Vs[r][sc * 4] = *(const float4*)&Vg[base + (size_t)(j0 + r) * DD + sc * 4];
        }
        {
            int r = t >> 2, c = (t & 3) * 16;
            *(int4*)&As[r][c] = *(const int4*)&A8[((size_t)b * NN + qt * QT + r) * NN + j0 + c];
        }
        __syncthreads();

        float s0[8], s1[8];
        #pragma unroll
        for (int e = 0; e < 8; ++e) { s0[e] = 0.f; s1[e] = 0.f; }
        #pragma unroll
        for (int i = 0; i < 8; ++i) {
            float4 qa = *(const float4*)&Qs[qg][i * 4];
            float4 qb = *(const float4*)&Qs[qg + 32][i * 4];
            #pragma unroll
            for (int e = 0; e < 8; ++e) {
                float4 kv = *(const float4*)&Ks[e * 8 + lane8][i * 4];
                s0[e] = fmaf(qa.x, kv.x, s0[e]); s0[e] = fmaf(qa.y, kv.y, s0[e]);
                s0[e] = fmaf(qa.z, kv.z, s0[e]); s0[e] = fmaf(qa.w, kv.w, s0[e]);
                s1[e] = fmaf(qb.x, kv.x, s1[e]); s1[e] = fmaf(qb.y, kv.y, s1[e]);
                s1[e] = fmaf(qb.z, kv.z, s1[e]); s1[e] = fmaf(qb.w, kv.w, s1[e]);
            }
        }

        float tm0 = -INFINITY, tm1 = -INFINITY;
        #pragma unroll
        for (int e = 0; e < 8; ++e) {
            bool valid = (j0 + e * 8 + lane8) < len;
            s0[e] = valid ? s0[e] : -INFINITY;
            s1[e] = valid ? s1[e] : -INFINITY;
            tm0 = fmaxf(tm0, s0[e]); tm1 = fmaxf(tm1, s1[e]);
        }
        #pragma unroll
        for (int off = 1; off < 8; off <<= 1) {
            tm0 = fmaxf(tm0, __shfl_xor(tm0, off, 8));
            tm1 = fmaxf(tm1, __shfl_xor(tm1, off, 8));
        }
        if (tm0 > m0) {
            float scl = __expf(m0 - tm0);
            l0 *= scl; pr0_1 *= scl; pr0_2 *= scl; po0_1 *= scl; po0_2 *= scl;
            #pragma unroll
            for (int d = 0; d < 32; ++d) acc0[d] *= scl;
            m0 = tm0;
        }
        if (tm1 > m1) {
            float scl = __expf(m1 - tm1);
            l1 *= scl; pr1_1 *= scl; pr1_2 *= scl; po1_1 *= scl; po1_2 *= scl;
            #pragma unroll
            for (int d = 0; d < 32; ++d) acc1[d] *= scl;
            m1 = tm1;
        }

        #pragma unroll
        for (int e = 0; e < 8; ++e) {
            int j = e * 8 + lane8;
            float pe0 = __expf(s0[e] - m0);
            float pe1 = __expf(s1[e] - m1);
            l0 += pe0; l1 += pe1;
            int a0 = As[qg][j], a1 = As[qg + 32][j];
            float w0 = exp2f((float)a0 * l2a);
            float w1 = exp2f((float)a1 * l2a);
            float pw0 = pe0 * w0, pw1 = pe1 * w1;
            pr0_1 += (a0 == 1) ? pe0 : 0.f;  pr0_2 += (a0 > 1) ? pe0 : 0.f;
            po0_1 += (a0 == 1) ? pw0 : 0.f;  po0_2 += (a0 > 1) ? pw0 : 0.f;
            pr1_1 += (a1 == 1) ? pe1 : 0.f;  pr1_2 += (a1 > 1) ? pe1 : 0.f;
            po1_1 += (a1 == 1) ? pw1 : 0.f;  po1_2 += (a1 > 1) ? pw1 : 0.f;
            s0[e] = pw0; s1[e] = pw1;
        }

        #pragma unroll
        for (int e = 0; e < 8; ++e) {
            float pw0 = s0[e], pw1 = s1[e];
            #pragma unroll
            for (int i = 0; i < 8; ++i) {
                float4 vv = *(const float4*)&Vs[e * 8 + lane8][i * 4];
                acc0[i * 4 + 0] = fmaf(pw0, vv.x, acc0[i * 4 + 0]);
                acc0[i * 4 + 1] = fmaf(pw0, vv.y, acc0[i * 4 + 1]);
                acc0[i * 4 + 2] = fmaf(pw0, vv.z, acc0[i * 4 + 2]);
                acc0[i * 4 + 3] = fmaf(pw0, vv.w, acc0[i * 4 + 3]);
                acc1[i * 4 + 0] = fmaf(pw1, vv.x, acc1[i * 4 + 0]);
                acc1[i * 4 + 1] = fmaf(pw1, vv.y, acc1[i * 4 + 1]);
                acc1[i * 4 + 2] = fmaf(pw1, vv.z, acc1[i * 4 + 2]);
                acc1[i * 4 + 3] = fmaf(pw1, vv.w, acc1[i * 4 + 3]);
            }
        }
    }

    #pragma unroll
    for (int off = 1; off < 8; off <<= 1) {
        l0 += __shfl_xor(l0, off, 8);       l1 += __shfl_xor(l1, off, 8);
        pr0_1 += __shfl_xor(pr0_1, off, 8); pr0_2 += __shfl_xor(pr0_2, off, 8);
        po0_1 += __shfl_xor(po0_1, off, 8); po0_2 += __shfl_xor(po0_2, off, 8);
        pr1_1 += __shfl_xor(pr1_1, off, 8); pr1_2 += __shfl_xor(pr1_2, off, 8);
        po1_1 += __shfl_xor(po1_1, off, 8); po1_2 += __shfl_xor(po1_2, off, 8);
        #pragma unroll
        for (int d = 0; d < 32; ++d) {
            acc0[d] += __shfl_xor(acc0[d], off, 8);
            acc1[d] += __shfl_xor(acc1[d], off, 8);
        }
    }

    const int dsl = lane8 * 4;
    float* st0 = part + (((size_t)split * 1024 + bid) * 64 + qg) * 40;
    float* st1 = st0 + 32 * 40;
    if (lane8 == 0) {
        st0[0] = m0; st0[1] = l0; st0[2] = pr0_1; st0[3] = pr0_2; st0[4] = po0_1; st0[5] = po0_2;
        st1[0] = m1; st1[1] = l1; st1[2] = pr1_1; st1[3] = pr1_2; st1[4] = po1_1; st1[5] = po1_2;
    }
    *(float4*)&st0[8 + dsl] = make_float4(acc0[dsl], acc0[dsl + 1], acc0[dsl + 2], acc0[dsl + 3]);
    *(float4*)&st1[8 + dsl] = make_float4(acc1[dsl], acc1[dsl + 1], acc1[dsl + 2], acc1[dsl + 3]);
}

// merge + fused fin (last-block-done protocol)
__global__ __launch_bounds__(256) void merge_kernel(
    const float* __restrict__ part, const int* __restrict__ lengths,
    const unsigned long long* __restrict__ cnt,
    float* __restrict__ out, double* __restrict__ sums,
    unsigned* __restrict__ done, float* __restrict__ outtail)
{
    const int bid = blockIdx.x;
    const int qt = bid & 15;
    const int hh = (bid >> 4) & 7;
    const int b  = bid >> 7;
    const int t  = threadIdx.x;
    const int qg = t >> 3;
    const int lane8 = t & 7;
    const int dsl = lane8 * 4;
    const int len = lengths[b];
    const size_t base = ((size_t)b * HH + hh) * NN * DD;
    const bool padded = (qt * QT >= len);   // block-uniform

    __shared__ float red4[4][4];

    if (padded) {
        float4 z = make_float4(0.f, 0.f, 0.f, 0.f);
        *(float4*)&out[base + (size_t)(qt * QT + qg) * DD + dsl] = z;
        *(float4*)&out[base + (size_t)(qt * QT + qg + 32) * DD + dsl] = z;
    } else {
        float v1 = 0.f, v2 = 0.f, v3 = 0.f, v4 = 0.f;
        #pragma unroll
        for (int rr = 0; rr < 2; ++rr) {
            const int row = qg + rr * 32;
            const int gq = qt * QT + row;
            const float* sA = part + (((size_t)0 * 1024 + bid) * 64 + row) * 40;
            const float* sB = part + (((size_t)1 * 1024 + bid) * 64 + row) * 40;
            float mA = sA[0], lA = sA[1], mB = sB[0], lB = sB[1];
            float ms = fmaxf(mA, mB);
            float fA = __expf(mA - ms), fB = __expf(mB - ms);
            float L = lA * fA + lB * fB;
            float inv = (gq < len) ? 1.f / L : 0.f;
            float4 aA = *(const float4*)&sA[8 + dsl];
            float4 aB = *(const float4*)&sB[8 + dsl];
            float4 o;
            o.x = (aA.x * fA + aB.x * fB) * inv;
            o.y = (aA.y * fA + aB.y * fB) * inv;
            o.z = (aA.z * fA + aB.z * fB) * inv;
            o.w = (aA.w * fA + aB.w * fB) * inv;
            *(float4*)&out[base + (size_t)gq * DD + dsl] = o;
            if (lane8 == 0) {
                v1 += (sA[2] * fA + sB[2] * fB) * inv;
                v2 += (sA[3] * fA + sB[3] * fB) * inv;
                v3 += (sA[4] * fA + sB[4] * fB) * inv;
                v4 += (sA[5] * fA + sB[5] * fB) * inv;
            }
        }

        #pragma unroll
        for (int off = 1; off < 64; off <<= 1) {
            v1 += __shfl_xor(v1, off);
            v2 += __shfl_xor(v2, off);
            v3 += __shfl_xor(v3, off);
            v4 += __shfl_xor(v4, off);
        }
        const int wv = t >> 6;
        if ((t & 63) == 0) { red4[0][wv] = v1; red4[1][wv] = v2; red4[2][wv] = v3; red4[3][wv] = v4; }
        __syncthreads();
        if (t == 0) {
            // t0 issues ALL sums atomics so its threadfence orders them
            #pragma unroll
            for (int q = 0; q < 4; ++q) {
                float s = red4[q][0] + red4[q][1] + red4[q][2] + red4[q][3];
                atomicAdd(&sums[q * 32], (double)s);
            }
        }
    }

    // every block increments done exactly once; last block computes the tail
    if (t == 0) {
        __threadfence();
        unsigned prev = atomicAdd(done, 1u);
        if (prev == 1023u) {
            __threadfence();
            double c1 = (double)(cnt[0] * (unsigned long long)HH);
            double c2 = (double)(cnt[32] * (unsigned long long)HH);
            outtail[0] = (float)(sums[0]  / c1);
            outtail[1] = (float)(sums[32] / c2);
            outtail[2] = (float)(sums[64] / c1);
            outtail[3] = (float)(sums[96] / c2);
        }
    }
}

extern "C" void kernel_launch(void* const* d_in, const int* in_sizes, int n_in,
                              void* d_out, int out_size, void* d_ws, size_t ws_size,
                              hipStream_t stream)
{
    const float* h   = (const float*)d_in[0];
    const int* A     = (const int*)d_in[1];
    const int* lens  = (const int*)d_in[2];
    const float* alp = (const float*)d_in[3];
    const float* Wq  = (const float*)d_in[4];
    const float* bq  = (const float*)d_in[5];
    const float* Wk  = (const float*)d_in[6];
    const float* bk  = (const float*)d_in[7];
    const float* Wv  = (const float*)d_in[8];
    const float* bv  = (const float*)d_in[9];

    float* outF = (float*)d_out;

    const size_t qkv = (size_t)BB * HH * NN * DD;
    float* Qw = (float*)d_ws;
    float* Kw = Qw + qkv;
    float* Vw = Kw + qkv;
    unsigned char* A8 = (unsigned char*)(Vw + qkv);
    double* sums = (double*)(A8 + (size_t)BB * NN * NN);
    unsigned long long* cnt = (unsigned long long*)(sums + 128);
    unsigned* done = (unsigned*)(cnt + 64);
    float* part = (float*)(done + 4);

    // zero sums[128] + cnt[64] + done[4]
    (void)hipMemsetAsync(sums, 0, 128 * sizeof(double) + 64 * sizeof(unsigned long long) + 16, stream);

    projpack_kernel<<<PROJ_BLOCKS + PACK_BLOCKS, 256, 0, stream>>>(
        h, Wq, bq, Wk, bk, Wv, bv, lens, A, Qw, Kw, Vw, A8, cnt);
    attn_split_kernel<<<2048, 256, 0, stream>>>(Qw, Kw, Vw, A8, lens, alp, part);
    merge_kernel<<<1024, 256, 0, stream>>>(part, lens, cnt, outF, sums, done, outF + qkv);
}